// Round 16
// baseline (185.512 us; speedup 1.0000x reference)
//
#include <hip/hip_runtime.h>
#include <hip/hip_bf16.h>
#include <cstdint>
#include <cstddef>

#define B_ 4
#define S_ 1024
#define D_ 1024
#define H_ 16
#define DEPTH_ 64
#define M_ (B_*S_)   // 4096 rows total

typedef __attribute__((ext_vector_type(4))) float f32x4;
typedef __attribute__((ext_vector_type(8))) __bf16 bf16x8;
typedef __attribute__((ext_vector_type(8))) unsigned short u16x8;
typedef __attribute__((ext_vector_type(4))) unsigned short u16x4;

typedef const __attribute__((address_space(1))) unsigned int GU32;
typedef __attribute__((address_space(3))) unsigned int LU32;

__device__ __forceinline__ unsigned short f2bf(float f) {
  unsigned int u = __builtin_bit_cast(unsigned int, f);
  u += 0x7FFFu + ((u >> 16) & 1u);   // round-to-nearest-even
  return (unsigned short)(u >> 16);
}

__device__ __forceinline__ float bf2f(unsigned short v) {
  unsigned int u = (unsigned int)v << 16;
  return __builtin_bit_cast(float, u);
}

// ---------------- f32 -> bf16 converts: 4 weights in ONE launch ------------
struct CvtAll { const float* s[4]; unsigned short* d[4]; };

__device__ __forceinline__ void cvt_body(const float* __restrict__ s,
                                         unsigned short* __restrict__ d, int i) {
  const f32x4* sp = (const f32x4*)s + (size_t)i * 2;
  f32x4 a = sp[0], b = sp[1];
  u16x8 o;
  o[0]=f2bf(a[0]); o[1]=f2bf(a[1]); o[2]=f2bf(a[2]); o[3]=f2bf(a[3]);
  o[4]=f2bf(b[0]); o[5]=f2bf(b[1]); o[6]=f2bf(b[2]); o[7]=f2bf(b[3]);
  *((u16x8*)d + i) = o;
}

// grid 2048: 4 weights x 512 blocks. No tails.
__global__ void cvt_all_kernel(CvtAll a) {
  const int bi = blockIdx.x;
  const int seg = bi >> 9;
  const int i = ((bi & 511) << 8) + threadIdx.x;
  cvt_body(a.s[seg], a.d[seg], i);
}

// ---------------- NT GEMM body (128x128): C = (A B^T + bias)*scale --------
// AF32/BF32: that operand is f32, reg-staged with in-flight f2bf (identical
// rounding to cvt -> bit-identical); else bf16 via global_load_lds.
template<bool AF32, bool BF32>
__device__ __forceinline__ void gemm_body(
    const unsigned short* __restrict__ Abf,
    const float* __restrict__ Af32,
    const unsigned short* __restrict__ Bbf,
    const float* __restrict__ Bf32,
    unsigned short* __restrict__ Obf,
    float* __restrict__ Of32,
    const float* __restrict__ bias,
    int N, int K, float scale, int biasRow, int m0, int n0)
{
  __shared__ unsigned short As[128*32];
  __shared__ unsigned short Bs[128*32];
  const int tid  = threadIdx.x;
  const int lane = tid & 63;
  const int w    = tid >> 6;
  const int wm   = w >> 1, wn = w & 1;
  const int fr   = lane & 15, kg = lane >> 4;

  f32x4 acc[4][4];
  #pragma unroll
  for (int i = 0; i < 4; ++i)
    #pragma unroll
    for (int j = 0; j < 4; ++j)
      acc[i][j] = (f32x4)0.0f;

  const int o0 = tid * 16,        o1 = (256 + tid) * 16;
  const int r0 = o0 >> 6,         c0 = (o0 & 63) >> 1;
  const int r1 = o1 >> 6,         c1 = (o1 & 63) >> 1;
  const int lds0 = (w * 64) * 16;
  const int lds1 = (256 + w * 64) * 16;

  const int rr = tid >> 1;            // reg-stage row
  const int rc = (tid & 1) * 16;      // reg-stage col base

  const int nkt = K >> 5;
  for (int kt = 0; kt < nkt; ++kt) {
    const int kk = kt * 32;
    if constexpr (!BF32) {
      __builtin_amdgcn_global_load_lds((GU32*)(Bbf + (size_t)(n0 + r0) * K + kk + c0),
                                       (LU32*)((char*)Bs + lds0), 16, 0, 0);
      __builtin_amdgcn_global_load_lds((GU32*)(Bbf + (size_t)(n0 + r1) * K + kk + c1),
                                       (LU32*)((char*)Bs + lds1), 16, 0, 0);
    }
    if constexpr (!AF32) {
      __builtin_amdgcn_global_load_lds((GU32*)(Abf + (size_t)(m0 + r0) * K + kk + c0),
                                       (LU32*)((char*)As + lds0), 16, 0, 0);
      __builtin_amdgcn_global_load_lds((GU32*)(Abf + (size_t)(m0 + r1) * K + kk + c1),
                                       (LU32*)((char*)As + lds1), 16, 0, 0);
    }
    if constexpr (AF32) {
      const float* as_ = Af32 + (size_t)(m0 + rr) * K + kk + rc;
      f32x4 a0 = *(const f32x4*)(as_);
      f32x4 a1 = *(const f32x4*)(as_ + 4);
      f32x4 a2 = *(const f32x4*)(as_ + 8);
      f32x4 a3 = *(const f32x4*)(as_ + 12);
      u16x8 q0, q1;
      q0[0]=f2bf(a0[0]); q0[1]=f2bf(a0[1]); q0[2]=f2bf(a0[2]); q0[3]=f2bf(a0[3]);
      q0[4]=f2bf(a1[0]); q0[5]=f2bf(a1[1]); q0[6]=f2bf(a1[2]); q0[7]=f2bf(a1[3]);
      q1[0]=f2bf(a2[0]); q1[1]=f2bf(a2[1]); q1[2]=f2bf(a2[2]); q1[3]=f2bf(a2[3]);
      q1[4]=f2bf(a3[0]); q1[5]=f2bf(a3[1]); q1[6]=f2bf(a3[2]); q1[7]=f2bf(a3[3]);
      *(u16x8*)((char*)As + tid * 32)      = q0;
      *(u16x8*)((char*)As + tid * 32 + 16) = q1;
    }
    if constexpr (BF32) {
      const float* bs_ = Bf32 + (size_t)(n0 + rr) * K + kk + rc;
      f32x4 a0 = *(const f32x4*)(bs_);
      f32x4 a1 = *(const f32x4*)(bs_ + 4);
      f32x4 a2 = *(const f32x4*)(bs_ + 8);
      f32x4 a3 = *(const f32x4*)(bs_ + 12);
      u16x8 q0, q1;
      q0[0]=f2bf(a0[0]); q0[1]=f2bf(a0[1]); q0[2]=f2bf(a0[2]); q0[3]=f2bf(a0[3]);
      q0[4]=f2bf(a1[0]); q0[5]=f2bf(a1[1]); q0[6]=f2bf(a1[2]); q0[7]=f2bf(a1[3]);
      q1[0]=f2bf(a2[0]); q1[1]=f2bf(a2[1]); q1[2]=f2bf(a2[2]); q1[3]=f2bf(a2[3]);
      q1[4]=f2bf(a3[0]); q1[5]=f2bf(a3[1]); q1[6]=f2bf(a3[2]); q1[7]=f2bf(a3[3]);
      *(u16x8*)((char*)Bs + tid * 32)      = q0;
      *(u16x8*)((char*)Bs + tid * 32 + 16) = q1;
    }
    __syncthreads();

    bf16x8 af[4], bf[4];
    #pragma unroll
    for (int i = 0; i < 4; ++i)
      af[i] = *(const bf16x8*)&As[(wm * 64 + i * 16 + fr) * 32 + kg * 8];
    #pragma unroll
    for (int j = 0; j < 4; ++j)
      bf[j] = *(const bf16x8*)&Bs[(wn * 64 + j * 16 + fr) * 32 + kg * 8];
    #pragma unroll
    for (int i = 0; i < 4; ++i)
      #pragma unroll
      for (int j = 0; j < 4; ++j)
        acc[i][j] = __builtin_amdgcn_mfma_f32_16x16x32_bf16(af[i], bf[j], acc[i][j], 0, 0, 0);
    __syncthreads();
  }

  #pragma unroll
  for (int i = 0; i < 4; ++i) {
    const int rowb = m0 + wm * 64 + i * 16 + kg * 4;
    #pragma unroll
    for (int j = 0; j < 4; ++j) {
      const int col = n0 + wn * 64 + j * 16 + fr;
      const float bcol = biasRow ? 0.0f : bias[col];
      #pragma unroll
      for (int r = 0; r < 4; ++r) {
        const int row = rowb + r;
        const float bv = biasRow ? bias[row] : bcol;
        const float val = (acc[i][j][r] + bv) * scale;
        if (Obf) Obf[(size_t)row * N + col] = f2bf(val);
        else     Of32[(size_t)row * N + col] = val;
      }
    }
  }
}

struct GemmSet { const unsigned short* A; const float* Af;
                 const unsigned short* Bm; const float* Bf;
                 unsigned short* O; const float* bias; };

__launch_bounds__(256)
__global__ void qkv_gemm(GemmSet s0, GemmSet s1, GemmSet s2) {
  const int z = blockIdx.y;
  GemmSet s = (z == 0) ? s0 : (z == 1) ? s1 : s2;
  if (z < 2) {   // Q/K: A = raw f32 input (convert-on-stage), B = bf16 weight
    const int m0 = (blockIdx.x & 31) * 128, n0 = (blockIdx.x >> 5) * 128;
    gemm_body<true, false>(nullptr, s.Af, s.Bm, nullptr, s.O, nullptr, s.bias,
                           D_, D_, (z == 0) ? 0.125f : 1.0f, 0, m0, n0);
  } else {       // V^T: A = bf16 weight, B = raw f32 v (convert-on-stage)
    const int m0 = (blockIdx.x & 7) * 128,  n0 = (blockIdx.x >> 3) * 128;
    gemm_body<false, true>(s.A, nullptr, nullptr, s.Bf, s.O, nullptr, s.bias,
                           M_, D_, 1.0f, 1, m0, n0);
  }
}

// ---------------- dense GEMM, 64x128 tile: 512 blocks = 2 blocks/CU --------
// Same BK=32 K-loop / accumulation order as gemm_body -> bit-identical math.
__launch_bounds__(256)
__global__ void dense_gemm(const unsigned short* __restrict__ A,
                           const unsigned short* __restrict__ Bm,
                           float* __restrict__ O, const float* __restrict__ bias) {
  __shared__ unsigned short As[64*32];     // 4 KB
  __shared__ unsigned short Bs[128*32];    // 8 KB
  const int tid  = threadIdx.x;
  const int lane = tid & 63;
  const int w    = tid >> 6;
  const int wm   = w >> 1, wn = w & 1;     // 2 row-halves x 2 col-halves
  const int fr   = lane & 15, kg = lane >> 4;
  const int m0   = blockIdx.x * 64, n0 = blockIdx.y * 128;
  const int K = D_, N = D_;

  f32x4 acc[2][4];
  #pragma unroll
  for (int i = 0; i < 2; ++i)
    #pragma unroll
    for (int j = 0; j < 4; ++j)
      acc[i][j] = (f32x4)0.0f;

  const int oA = tid * 16;
  const int rA = oA >> 6,  cA = (oA & 63) >> 1;
  const int o0 = tid * 16, o1 = (256 + tid) * 16;
  const int r0 = o0 >> 6,  c0 = (o0 & 63) >> 1;
  const int r1 = o1 >> 6,  c1 = (o1 & 63) >> 1;
  const int ldsA = w * 1024;
  const int lds0 = (w * 64) * 16;
  const int lds1 = (256 + w * 64) * 16;

  for (int kt = 0; kt < (K >> 5); ++kt) {
    const int kk = kt * 32;
    __builtin_amdgcn_global_load_lds((GU32*)(Bm + (size_t)(n0 + r0) * K + kk + c0),
                                     (LU32*)((char*)Bs + lds0), 16, 0, 0);
    __builtin_amdgcn_global_load_lds((GU32*)(Bm + (size_t)(n0 + r1) * K + kk + c1),
                                     (LU32*)((char*)Bs + lds1), 16, 0, 0);
    __builtin_amdgcn_global_load_lds((GU32*)(A + (size_t)(m0 + rA) * K + kk + cA),
                                     (LU32*)((char*)As + ldsA), 16, 0, 0);
    __syncthreads();

    bf16x8 af[2], bf[4];
    #pragma unroll
    for (int i = 0; i < 2; ++i)
      af[i] = *(const bf16x8*)&As[(wm * 32 + i * 16 + fr) * 32 + kg * 8];
    #pragma unroll
    for (int j = 0; j < 4; ++j)
      bf[j] = *(const bf16x8*)&Bs[(wn * 64 + j * 16 + fr) * 32 + kg * 8];
    #pragma unroll
    for (int i = 0; i < 2; ++i)
      #pragma unroll
      for (int j = 0; j < 4; ++j)
        acc[i][j] = __builtin_amdgcn_mfma_f32_16x16x32_bf16(af[i], bf[j], acc[i][j], 0, 0, 0);
    __syncthreads();
  }

  #pragma unroll
  for (int i = 0; i < 2; ++i) {
    const int rowb = m0 + wm * 32 + i * 16 + kg * 4;
    #pragma unroll
    for (int j = 0; j < 4; ++j) {
      const int col = n0 + wn * 64 + j * 16 + fr;
      const float bcol = bias[col];
      #pragma unroll
      for (int r = 0; r < 4; ++r)
        O[(size_t)(rowb + r) * N + col] = acc[i][j][r] + bcol;
    }
  }
}

// ---------------- fused attention v9 + T5 setprio: per-wave autonomy -------
// grid 4096 blocks, 512 threads (8 waves). Per block: 16 q-rows, k = 1024.
// QK: wave w owns k-strip [w*128,(w+1)*128), 8 iters of 16k, private dbuf.
// PV: wave w -> (d-tile fd=w&3, k-half kh=w>>2), 8 iters of 64k; partials of
// waves 4-7 reduced by waves 0-3 through LDS. Mask lives in registers.
// Barriers: 1 mid (P/ssum), 1 epilogue (PV partials). None in loops.
// s_setprio(1) wraps both MFMA clusters (T5; per-wave role diversity regime).
// LDS 80KB exact: P [0,32K) | 8 regions x 6KB [32K,80K):
//   region: K0 2K | K1 2K | A0 1K (-> ssum) | A1 1K (-> PV partials)
__launch_bounds__(512, 4)
__global__ void attn_kernel(const unsigned short* __restrict__ qp,
                            const unsigned short* __restrict__ kp,
                            const unsigned short* __restrict__ vt,
                            const float* __restrict__ mask,
                            const float* __restrict__ adjoin,
                            float* __restrict__ attn_out,
                            unsigned short* __restrict__ ctx)
{
  __shared__ __align__(16) char L[81920];
  char* const Pb = L;                       // P bf16 [16][2048B], XOR-swizzled
  char* const Rg = L + 32768;               // 8 x 6144B wave regions

  const int tid = threadIdx.x, lane = tid & 63, w = tid >> 6;
  const int fr = lane & 15, kg = lane >> 4;
  const int fd = w & 3, kh = w >> 2;
  const int frsw = (fr & 7) << 4;
  const int r8 = lane >> 3;
  const int c7p = (((lane & 7) ^ r8) << 4);

  char* const Wb  = Rg + w * 6144;
  char* const Ks0 = Wb,        * const Ks1 = Wb + 2048;
  char* const Ab0 = Wb + 4096, * const Ab1 = Wb + 5120;

  // XCD map: XCD x=i&7 owns bh in [8x,8x+8); adjoin tile reused by 8 heads.
  const int i_ = blockIdx.x;
  const int bh = (i_ & 7) * 8 + ((i_ >> 3) & 7);
  const int qt = i_ >> 6;
  const int b = bh >> 4, h = bh & 15;
  const int q0 = qt * 16;
  const int kw = w * 128;                   // wave k-strip base

  const char* kG = (const char*)(kp + (size_t)b * S_ * D_ + h * DEPTH_);
  const char* aG = (const char*)(adjoin + (size_t)b * S_ * S_ + (size_t)q0 * S_);
  const char* vG = (const char*)(vt + (size_t)h * DEPTH_ * M_ + (size_t)b * S_);
  const char* mG = (const char*)(mask + (size_t)b * S_);

  auto stageK = [&](int t, char* dst) {
    #pragma unroll
    for (int j = 0; j < 2; ++j)
      __builtin_amdgcn_global_load_lds(
          (GU32*)(kG + (size_t)(kw + t * 16 + j * 8 + r8) * 2048 + c7p),
          (LU32*)(dst + j * 1024 + lane * 16), 16, 0, 0);
  };
  auto stageA = [&](int t, char* dst) {   // 16q x 16k f32, row=64B, linear
    __builtin_amdgcn_global_load_lds(
        (GU32*)(aG + (size_t)(lane >> 2) * 4096 + kw * 4 + t * 64 + (lane & 3) * 16),
        (LU32*)(dst + lane * 16), 16, 0, 0);
  };
  auto stageV = [&](int t, char* dst) {   // 16 d-rows x 64k of this wave's kh
    #pragma unroll
    for (int j = 0; j < 2; ++j)
      __builtin_amdgcn_global_load_lds(
          (GU32*)(vG + (size_t)(fd * 16 + j * 8 + r8) * 8192 + kh * 1024 + t * 128 + c7p),
          (LU32*)(dst + j * 1024 + lane * 16), 16, 0, 0);
  };

  // ---- Q + mask register loads FIRST (oldest in vmcnt queue)
  const unsigned short* qrow = qp + ((size_t)b * S_ + q0 + fr) * D_ + h * DEPTH_;
  bf16x8 qf0 = *(const bf16x8*)&qrow[kg * 8];
  bf16x8 qf1 = *(const bf16x8*)&qrow[32 + kg * 8];
  f32x4 mreg[8];
  #pragma unroll
  for (int t = 0; t < 8; ++t)
    mreg[t] = *(const f32x4*)(mG + kw * 4 + t * 64 + kg * 16);
  asm volatile("" ::: "memory");          // pin loads before staging

  // ---- prologue staging: K0, A0, K1, A1 (3+3 loads)
  stageK(0, Ks0); stageA(0, Ab0);
  stageK(1, Ks1); stageA(1, Ab1);
  asm volatile("s_waitcnt vmcnt(3)" ::: "memory");   // Q,mask,K0,A0 done
  __builtin_amdgcn_sched_barrier(0);

  float ls = 0.0f;

  // ---- QK loop: 8 per-wave iterations, no barriers
  #pragma unroll
  for (int t = 0; t < 8; ++t) {
    if (t == 7)     asm volatile("s_waitcnt vmcnt(2)" ::: "memory");
    else if (t > 0) asm volatile("s_waitcnt vmcnt(3)" ::: "memory");
    __builtin_amdgcn_sched_barrier(0);

    const char* kb = (t & 1) ? Ks1 : Ks0;
    const char* ab = (t & 1) ? Ab1 : Ab0;
    bf16x8 kf0 = *(const bf16x8*)(kb + fr * 128 + ((kg * 16) ^ frsw));
    bf16x8 kf1 = *(const bf16x8*)(kb + fr * 128 + ((64 + kg * 16) ^ frsw));
    f32x4 a4  = *(const f32x4*)(ab + fr * 64 + kg * 16);

    asm volatile("s_waitcnt lgkmcnt(0)" ::: "memory");  // buffers free
    __builtin_amdgcn_sched_barrier(0);

    if (t < 6)      { stageK(t + 2, (t & 1) ? Ks1 : Ks0);
                      stageA(t + 2, (t & 1) ? Ab1 : Ab0); }
    else if (t == 6)  stageV(0, Ks0);   // K0 just consumed
    else              stageV(1, Ks1);   // K1 just consumed

    __builtin_amdgcn_s_setprio(1);
    f32x4 s = (f32x4)0.0f;
    s = __builtin_amdgcn_mfma_f32_16x16x32_bf16(kf0, qf0, s, 0, 0, 0);
    s = __builtin_amdgcn_mfma_f32_16x16x32_bf16(kf1, qf1, s, 0, 0, 0);
    __builtin_amdgcn_s_setprio(0);

    f32x4 p;
    #pragma unroll
    for (int r = 0; r < 4; ++r)
      p[r] = __expf(s[r] + a4[r] + mreg[t][r] * (-1e9f));
    ls += (p[0] + p[1]) + (p[2] + p[3]);
    u16x4 pk;
    #pragma unroll
    for (int r = 0; r < 4; ++r) pk[r] = f2bf(p[r]);
    *(u16x4*)(Pb + fr * 2048 + ((kw * 2 + t * 32 + kg * 8) ^ frsw)) = pk;
  }

  // ---- strip sums -> own A0 slot
  ls += __shfl_xor(ls, 16);
  ls += __shfl_xor(ls, 32);
  if (lane < 16) *(float*)(Ab0 + lane * 4) = ls;

  // ---- mid barrier: P + ssum visible; V0,V1 still in flight
  asm volatile("s_waitcnt lgkmcnt(0)" ::: "memory");
  __builtin_amdgcn_s_barrier();
  __builtin_amdgcn_sched_barrier(0);

  // ---- PV loop: 8 per-wave iterations of 64k, no barriers
  f32x4 cacc = (f32x4)0.0f;
  #pragma unroll
  for (int t = 0; t < 8; ++t) {
    if (t == 7) asm volatile("s_waitcnt vmcnt(0)" ::: "memory");
    else        asm volatile("s_waitcnt vmcnt(2)" ::: "memory");
    __builtin_amdgcn_sched_barrier(0);

    const char* vb = (t & 1) ? Ks1 : Ks0;
    bf16x8 vf0 = *(const bf16x8*)(vb + fr * 128 + ((kg * 16) ^ frsw));
    bf16x8 vf1 = *(const bf16x8*)(vb + fr * 128 + ((64 + kg * 16) ^ frsw));
    bf16x8 pf0 = *(const bf16x8*)(Pb + fr * 2048 + ((kh * 1024 + t * 128 + kg * 16) ^ frsw));
    bf16x8 pf1 = *(const bf16x8*)(Pb + fr * 2048 + ((kh * 1024 + t * 128 + 64 + kg * 16) ^ frsw));

    asm volatile("s_waitcnt lgkmcnt(0)" ::: "memory");
    __builtin_amdgcn_sched_barrier(0);

    if (t < 6) stageV(t + 2, (t & 1) ? Ks1 : Ks0);

    __builtin_amdgcn_s_setprio(1);
    cacc = __builtin_amdgcn_mfma_f32_16x16x32_bf16(vf0, pf0, cacc, 0, 0, 0);
    cacc = __builtin_amdgcn_mfma_f32_16x16x32_bf16(vf1, pf1, cacc, 0, 0, 0);
    __builtin_amdgcn_s_setprio(0);
  }

  // ---- epilogue: waves 4-7 publish k-half partials; 0-3 reduce + ctx
  if (w >= 4) *(f32x4*)(Ab1 + lane * 16) = cacc;
  asm volatile("s_waitcnt lgkmcnt(0)" ::: "memory");
  __builtin_amdgcn_s_barrier();
  __builtin_amdgcn_sched_barrier(0);

  if (w < 4) {
    f32x4 red = *(const f32x4*)(Rg + (w + 4) * 6144 + 5120 + lane * 16);
    #pragma unroll
    for (int r = 0; r < 4; ++r) cacc[r] += red[r];
    float gs = 0.0f;
    #pragma unroll
    for (int w2 = 0; w2 < 8; ++w2)
      gs += *(const float*)(Rg + w2 * 6144 + 4096 + fr * 4);
    const float giC = 1.0f / gs;
    u16x4 cv;
    #pragma unroll
    for (int r = 0; r < 4; ++r) cv[r] = f2bf(cacc[r] * giC);
    *(u16x4*)&ctx[((size_t)b * S_ + q0 + fr) * D_ + h * DEPTH_ + fd * 16 + kg * 4] = cv;
  }

  // ---- attn store: 2 rows/wave from P-LDS, nontemporal full-line stores
  #pragma unroll
  for (int j = 0; j < 2; ++j) {
    const int row = w * 2 + j;
    float gs = 0.0f;
    #pragma unroll
    for (int w2 = 0; w2 < 8; ++w2)
      gs += *(const float*)(Rg + w2 * 6144 + 4096 + row * 4);
    const float g = 1.0f / gs;
    const char* pr = Pb + row * 2048;
    const int rs = (row & 7) << 4;
    float* ao = attn_out + ((size_t)bh * S_ + q0 + row) * S_;
    #pragma unroll
    for (int half = 0; half < 2; ++half) {
      u16x8 pv = *(const u16x8*)(pr + ((half * 1024 + lane * 16) ^ rs));
      f32x4 o0, o1;
      #pragma unroll
      for (int e = 0; e < 4; ++e) { o0[e] = bf2f(pv[e]) * g; o1[e] = bf2f(pv[4 + e]) * g; }
      __builtin_nontemporal_store(o0, (f32x4*)(ao + half * 512 + lane * 8));
      __builtin_nontemporal_store(o1, (f32x4*)(ao + half * 512 + lane * 8 + 4));
    }
  }
}

// ---------------- launcher ----------------
extern "C" void kernel_launch(void* const* d_in, const int* in_sizes, int n_in,
                              void* d_out, int out_size, void* d_ws, size_t ws_size,
                              hipStream_t stream)
{
  const float* v_in   = (const float*)d_in[0];
  const float* k_in   = (const float*)d_in[1];
  const float* q_in   = (const float*)d_in[2];
  const float* mask   = (const float*)d_in[3];
  const float* adjoin = (const float*)d_in[4];
  const float* wq_w   = (const float*)d_in[5];
  const float* wq_b   = (const float*)d_in[6];
  const float* wk_w   = (const float*)d_in[7];
  const float* wk_b   = (const float*)d_in[8];
  const float* wv_w   = (const float*)d_in[9];
  const float* wv_b   = (const float*)d_in[10];
  const float* wd_w   = (const float*)d_in[11];
  const float* wd_b   = (const float*)d_in[12];

  unsigned short* xq  = (unsigned short*)d_ws;      // unused (kept for layout)
  unsigned short* xk  = xq  + (size_t)M_ * D_;      // unused
  unsigned short* xv  = xk  + (size_t)M_ * D_;      // unused
  unsigned short* wqb = xv  + (size_t)M_ * D_;
  unsigned short* wkb = wqb + (size_t)D_ * D_;
  unsigned short* wvb = wkb + (size_t)D_ * D_;
  unsigned short* wdb = wvb + (size_t)D_ * D_;
  unsigned short* qp  = wdb + (size_t)D_ * D_;
  unsigned short* kp  = qp  + (size_t)M_ * D_;
  unsigned short* vt  = kp  + (size_t)M_ * D_;
  unsigned short* ctx = vt  + (size_t)M_ * D_;

  float* out  = (float*)d_out;                       // [B,S,D]
  float* attn = out + (size_t)B_ * S_ * D_;          // [B,H,S,S]

  CvtAll ca;
  ca.s[0] = wq_w; ca.s[1] = wk_w; ca.s[2] = wv_w; ca.s[3] = wd_w;
  ca.d[0] = wqb;  ca.d[1] = wkb;  ca.d[2] = wvb;  ca.d[3] = wdb;
  cvt_all_kernel<<<2048, 256, 0, stream>>>(ca);

  GemmSet sq{nullptr, q_in, wqb, nullptr, qp, wq_b};   // A: f32 q
  GemmSet sk{nullptr, k_in, wkb, nullptr, kp, wk_b};   // A: f32 k
  GemmSet sv{wvb, nullptr, nullptr, v_in, vt, wv_b};   // B: f32 v
  qkv_gemm<<<dim3(256, 3), 256, 0, stream>>>(sq, sk, sv);

  attn_kernel<<<B_ * H_ * (S_ / 16), 512, 0, stream>>>(qp, kp, vt, mask, adjoin, attn, ctx);

  dense_gemm<<<dim3(64, 8), 256, 0, stream>>>(ctx, wdb, out, wd_b);
}

// Round 17
// 182.921 us; speedup vs baseline: 1.0142x; 1.0142x over previous
//
#include <hip/hip_runtime.h>
#include <hip/hip_bf16.h>
#include <cstdint>
#include <cstddef>

#define B_ 4
#define S_ 1024
#define D_ 1024
#define H_ 16
#define DEPTH_ 64
#define M_ (B_*S_)   // 4096 rows total

typedef __attribute__((ext_vector_type(4))) float f32x4;
typedef __attribute__((ext_vector_type(8))) __bf16 bf16x8;
typedef __attribute__((ext_vector_type(8))) unsigned short u16x8;
typedef __attribute__((ext_vector_type(4))) unsigned short u16x4;

typedef const __attribute__((address_space(1))) unsigned int GU32;
typedef __attribute__((address_space(3))) unsigned int LU32;

__device__ __forceinline__ unsigned short f2bf(float f) {
  unsigned int u = __builtin_bit_cast(unsigned int, f);
  u += 0x7FFFu + ((u >> 16) & 1u);   // round-to-nearest-even
  return (unsigned short)(u >> 16);
}

__device__ __forceinline__ float bf2f(unsigned short v) {
  unsigned int u = (unsigned int)v << 16;
  return __builtin_bit_cast(float, u);
}

// ---------------- f32 -> bf16 converts: v + 4 weights in ONE launch --------
struct CvtAll { const float* s[5]; unsigned short* d[5]; };

__device__ __forceinline__ void cvt_body(const float* __restrict__ s,
                                         unsigned short* __restrict__ d, int i) {
  const f32x4* sp = (const f32x4*)s + (size_t)i * 2;
  f32x4 a = sp[0], b = sp[1];
  u16x8 o;
  o[0]=f2bf(a[0]); o[1]=f2bf(a[1]); o[2]=f2bf(a[2]); o[3]=f2bf(a[3]);
  o[4]=f2bf(b[0]); o[5]=f2bf(b[1]); o[6]=f2bf(b[2]); o[7]=f2bf(b[3]);
  *((u16x8*)d + i) = o;
}

// grid 4096: v = 2048 blocks; 4 weights = 512 each. No tails.
__global__ void cvt_all_kernel(CvtAll a) {
  int bi = blockIdx.x, seg, i;
  if (bi < 2048) { seg = 0;                i = (bi << 8) + threadIdx.x; }
  else { int t = bi - 2048; seg = 1 + (t >> 9); i = ((t & 511) << 8) + threadIdx.x; }
  cvt_body(a.s[seg], a.d[seg], i);
}

// ---------------- NT GEMM body (128x128): C = (A B^T + bias)*scale --------
// AF32: A is f32, reg-staged with in-flight f32->bf16 convert (same rounding
// as cvt kernel -> bit-identical results); else A bf16 via global_load_lds.
template<bool AF32>
__device__ __forceinline__ void gemm_body(
    const unsigned short* __restrict__ Abf,
    const float* __restrict__ Af32,
    const unsigned short* __restrict__ Bm,
    unsigned short* __restrict__ Obf,
    float* __restrict__ Of32,
    const float* __restrict__ bias,
    int N, int K, float scale, int biasRow, int m0, int n0)
{
  __shared__ unsigned short As[128*32];
  __shared__ unsigned short Bs[128*32];
  const int tid  = threadIdx.x;
  const int lane = tid & 63;
  const int w    = tid >> 6;
  const int wm   = w >> 1, wn = w & 1;
  const int fr   = lane & 15, kg = lane >> 4;

  f32x4 acc[4][4];
  #pragma unroll
  for (int i = 0; i < 4; ++i)
    #pragma unroll
    for (int j = 0; j < 4; ++j)
      acc[i][j] = (f32x4)0.0f;

  const int o0 = tid * 16,        o1 = (256 + tid) * 16;
  const int r0 = o0 >> 6,         c0 = (o0 & 63) >> 1;
  const int r1 = o1 >> 6,         c1 = (o1 & 63) >> 1;
  const int lds0 = (w * 64) * 16;
  const int lds1 = (256 + w * 64) * 16;

  const int nkt = K >> 5;
  for (int kt = 0; kt < nkt; ++kt) {
    const int kk = kt * 32;
    __builtin_amdgcn_global_load_lds((GU32*)(Bm + (size_t)(n0 + r0) * K + kk + c0),
                                     (LU32*)((char*)Bs + lds0), 16, 0, 0);
    __builtin_amdgcn_global_load_lds((GU32*)(Bm + (size_t)(n0 + r1) * K + kk + c1),
                                     (LU32*)((char*)Bs + lds1), 16, 0, 0);
    if constexpr (AF32) {
      const int ar = m0 + (tid >> 1);
      const int ac = (tid & 1) * 16;
      const float* as_ = Af32 + (size_t)ar * K + kk + ac;
      f32x4 a0 = *(const f32x4*)(as_);
      f32x4 a1 = *(const f32x4*)(as_ + 4);
      f32x4 a2 = *(const f32x4*)(as_ + 8);
      f32x4 a3 = *(const f32x4*)(as_ + 12);
      u16x8 q0, q1;
      q0[0]=f2bf(a0[0]); q0[1]=f2bf(a0[1]); q0[2]=f2bf(a0[2]); q0[3]=f2bf(a0[3]);
      q0[4]=f2bf(a1[0]); q0[5]=f2bf(a1[1]); q0[6]=f2bf(a1[2]); q0[7]=f2bf(a1[3]);
      q1[0]=f2bf(a2[0]); q1[1]=f2bf(a2[1]); q1[2]=f2bf(a2[2]); q1[3]=f2bf(a2[3]);
      q1[4]=f2bf(a3[0]); q1[5]=f2bf(a3[1]); q1[6]=f2bf(a3[2]); q1[7]=f2bf(a3[3]);
      *(u16x8*)((char*)As + tid * 32)      = q0;
      *(u16x8*)((char*)As + tid * 32 + 16) = q1;
    } else {
      __builtin_amdgcn_global_load_lds((GU32*)(Abf + (size_t)(m0 + r0) * K + kk + c0),
                                       (LU32*)((char*)As + lds0), 16, 0, 0);
      __builtin_amdgcn_global_load_lds((GU32*)(Abf + (size_t)(m0 + r1) * K + kk + c1),
                                       (LU32*)((char*)As + lds1), 16, 0, 0);
    }
    __syncthreads();

    bf16x8 af[4], bf[4];
    #pragma unroll
    for (int i = 0; i < 4; ++i)
      af[i] = *(const bf16x8*)&As[(wm * 64 + i * 16 + fr) * 32 + kg * 8];
    #pragma unroll
    for (int j = 0; j < 4; ++j)
      bf[j] = *(const bf16x8*)&Bs[(wn * 64 + j * 16 + fr) * 32 + kg * 8];
    #pragma unroll
    for (int i = 0; i < 4; ++i)
      #pragma unroll
      for (int j = 0; j < 4; ++j)
        acc[i][j] = __builtin_amdgcn_mfma_f32_16x16x32_bf16(af[i], bf[j], acc[i][j], 0, 0, 0);
    __syncthreads();
  }

  #pragma unroll
  for (int i = 0; i < 4; ++i) {
    const int rowb = m0 + wm * 64 + i * 16 + kg * 4;
    #pragma unroll
    for (int j = 0; j < 4; ++j) {
      const int col = n0 + wn * 64 + j * 16 + fr;
      const float bcol = biasRow ? 0.0f : bias[col];
      #pragma unroll
      for (int r = 0; r < 4; ++r) {
        const int row = rowb + r;
        const float bv = biasRow ? bias[row] : bcol;
        const float val = (acc[i][j][r] + bv) * scale;
        if (Obf) Obf[(size_t)row * N + col] = f2bf(val);
        else     Of32[(size_t)row * N + col] = val;
      }
    }
  }
}

struct GemmSet { const unsigned short* A; const float* Af;
                 const unsigned short* Bm; unsigned short* O; const float* bias; };

__launch_bounds__(256)
__global__ void qkv_gemm(GemmSet s0, GemmSet s1, GemmSet s2) {
  const int z = blockIdx.y;
  GemmSet s = (z == 0) ? s0 : (z == 1) ? s1 : s2;
  if (z < 2) {   // Q/K: A = raw f32 input, convert-on-stage
    const int m0 = (blockIdx.x & 31) * 128, n0 = (blockIdx.x >> 5) * 128;
    gemm_body<true>(nullptr, s.Af, s.Bm, s.O, nullptr, s.bias, D_, D_,
                    (z == 0) ? 0.125f : 1.0f, 0, m0, n0);
  } else {       // V^T: A = bf16 weight
    const int m0 = (blockIdx.x & 7) * 128,  n0 = (blockIdx.x >> 3) * 128;
    gemm_body<false>(s.A, nullptr, s.Bm, s.O, nullptr, s.bias, M_, D_,
                     1.0f, 1, m0, n0);
  }
}

// ---------------- dense GEMM, 64x128 tile: 512 blocks = 2 blocks/CU --------
// Same BK=32 K-loop / accumulation order as gemm_body -> bit-identical math.
__launch_bounds__(256)
__global__ void dense_gemm(const unsigned short* __restrict__ A,
                           const unsigned short* __restrict__ Bm,
                           float* __restrict__ O, const float* __restrict__ bias) {
  __shared__ unsigned short As[64*32];     // 4 KB
  __shared__ unsigned short Bs[128*32];    // 8 KB
  const int tid  = threadIdx.x;
  const int lane = tid & 63;
  const int w    = tid >> 6;
  const int wm   = w >> 1, wn = w & 1;     // 2 row-halves x 2 col-halves
  const int fr   = lane & 15, kg = lane >> 4;
  const int m0   = blockIdx.x * 64, n0 = blockIdx.y * 128;
  const int K = D_, N = D_;

  f32x4 acc[2][4];
  #pragma unroll
  for (int i = 0; i < 2; ++i)
    #pragma unroll
    for (int j = 0; j < 4; ++j)
      acc[i][j] = (f32x4)0.0f;

  // A: one 16B chunk per thread (4096B); B: two chunks as in gemm_body
  const int oA = tid * 16;
  const int rA = oA >> 6,  cA = (oA & 63) >> 1;
  const int o0 = tid * 16, o1 = (256 + tid) * 16;
  const int r0 = o0 >> 6,  c0 = (o0 & 63) >> 1;
  const int r1 = o1 >> 6,  c1 = (o1 & 63) >> 1;
  const int ldsA = w * 1024;               // 64 lanes x 16B per wave
  const int lds0 = (w * 64) * 16;
  const int lds1 = (256 + w * 64) * 16;

  for (int kt = 0; kt < (K >> 5); ++kt) {
    const int kk = kt * 32;
    __builtin_amdgcn_global_load_lds((GU32*)(Bm + (size_t)(n0 + r0) * K + kk + c0),
                                     (LU32*)((char*)Bs + lds0), 16, 0, 0);
    __builtin_amdgcn_global_load_lds((GU32*)(Bm + (size_t)(n0 + r1) * K + kk + c1),
                                     (LU32*)((char*)Bs + lds1), 16, 0, 0);
    __builtin_amdgcn_global_load_lds((GU32*)(A + (size_t)(m0 + rA) * K + kk + cA),
                                     (LU32*)((char*)As + ldsA), 16, 0, 0);
    __syncthreads();

    bf16x8 af[2], bf[4];
    #pragma unroll
    for (int i = 0; i < 2; ++i)
      af[i] = *(const bf16x8*)&As[(wm * 32 + i * 16 + fr) * 32 + kg * 8];
    #pragma unroll
    for (int j = 0; j < 4; ++j)
      bf[j] = *(const bf16x8*)&Bs[(wn * 64 + j * 16 + fr) * 32 + kg * 8];
    #pragma unroll
    for (int i = 0; i < 2; ++i)
      #pragma unroll
      for (int j = 0; j < 4; ++j)
        acc[i][j] = __builtin_amdgcn_mfma_f32_16x16x32_bf16(af[i], bf[j], acc[i][j], 0, 0, 0);
    __syncthreads();
  }

  #pragma unroll
  for (int i = 0; i < 2; ++i) {
    const int rowb = m0 + wm * 32 + i * 16 + kg * 4;
    #pragma unroll
    for (int j = 0; j < 4; ++j) {
      const int col = n0 + wn * 64 + j * 16 + fr;
      const float bcol = bias[col];
      #pragma unroll
      for (int r = 0; r < 4; ++r)
        O[(size_t)(rowb + r) * N + col] = acc[i][j][r] + bcol;
    }
  }
}

// ---------------- fused attention v9 + T5 setprio: per-wave autonomy -------
// grid 4096 blocks, 512 threads (8 waves). Per block: 16 q-rows, k = 1024.
// QK: wave w owns k-strip [w*128,(w+1)*128), 8 iters of 16k, private dbuf.
// PV: wave w -> (d-tile fd=w&3, k-half kh=w>>2), 8 iters of 64k; partials of
// waves 4-7 reduced by waves 0-3 through LDS. Mask lives in registers.
// Barriers: 1 mid (P/ssum), 1 epilogue (PV partials). None in loops.
// s_setprio(1) wraps both MFMA clusters (T5; per-wave role diversity regime).
// LDS 80KB exact: P [0,32K) | 8 regions x 6KB [32K,80K):
//   region: K0 2K | K1 2K | A0 1K (-> ssum) | A1 1K (-> PV partials)
__launch_bounds__(512, 4)
__global__ void attn_kernel(const unsigned short* __restrict__ qp,
                            const unsigned short* __restrict__ kp,
                            const unsigned short* __restrict__ vt,
                            const float* __restrict__ mask,
                            const float* __restrict__ adjoin,
                            float* __restrict__ attn_out,
                            unsigned short* __restrict__ ctx)
{
  __shared__ __align__(16) char L[81920];
  char* const Pb = L;                       // P bf16 [16][2048B], XOR-swizzled
  char* const Rg = L + 32768;               // 8 x 6144B wave regions

  const int tid = threadIdx.x, lane = tid & 63, w = tid >> 6;
  const int fr = lane & 15, kg = lane >> 4;
  const int fd = w & 3, kh = w >> 2;
  const int frsw = (fr & 7) << 4;
  const int r8 = lane >> 3;
  const int c7p = (((lane & 7) ^ r8) << 4);

  char* const Wb  = Rg + w * 6144;
  char* const Ks0 = Wb,        * const Ks1 = Wb + 2048;
  char* const Ab0 = Wb + 4096, * const Ab1 = Wb + 5120;

  // XCD map: XCD x=i&7 owns bh in [8x,8x+8); adjoin tile reused by 8 heads.
  const int i_ = blockIdx.x;
  const int bh = (i_ & 7) * 8 + ((i_ >> 3) & 7);
  const int qt = i_ >> 6;
  const int b = bh >> 4, h = bh & 15;
  const int q0 = qt * 16;
  const int kw = w * 128;                   // wave k-strip base

  const char* kG = (const char*)(kp + (size_t)b * S_ * D_ + h * DEPTH_);
  const char* aG = (const char*)(adjoin + (size_t)b * S_ * S_ + (size_t)q0 * S_);
  const char* vG = (const char*)(vt + (size_t)h * DEPTH_ * M_ + (size_t)b * S_);
  const char* mG = (const char*)(mask + (size_t)b * S_);

  auto stageK = [&](int t, char* dst) {
    #pragma unroll
    for (int j = 0; j < 2; ++j)
      __builtin_amdgcn_global_load_lds(
          (GU32*)(kG + (size_t)(kw + t * 16 + j * 8 + r8) * 2048 + c7p),
          (LU32*)(dst + j * 1024 + lane * 16), 16, 0, 0);
  };
  auto stageA = [&](int t, char* dst) {   // 16q x 16k f32, row=64B, linear
    __builtin_amdgcn_global_load_lds(
        (GU32*)(aG + (size_t)(lane >> 2) * 4096 + kw * 4 + t * 64 + (lane & 3) * 16),
        (LU32*)(dst + lane * 16), 16, 0, 0);
  };
  auto stageV = [&](int t, char* dst) {   // 16 d-rows x 64k of this wave's kh
    #pragma unroll
    for (int j = 0; j < 2; ++j)
      __builtin_amdgcn_global_load_lds(
          (GU32*)(vG + (size_t)(fd * 16 + j * 8 + r8) * 8192 + kh * 1024 + t * 128 + c7p),
          (LU32*)(dst + j * 1024 + lane * 16), 16, 0, 0);
  };

  // ---- Q + mask register loads FIRST (oldest in vmcnt queue)
  const unsigned short* qrow = qp + ((size_t)b * S_ + q0 + fr) * D_ + h * DEPTH_;
  bf16x8 qf0 = *(const bf16x8*)&qrow[kg * 8];
  bf16x8 qf1 = *(const bf16x8*)&qrow[32 + kg * 8];
  f32x4 mreg[8];
  #pragma unroll
  for (int t = 0; t < 8; ++t)
    mreg[t] = *(const f32x4*)(mG + kw * 4 + t * 64 + kg * 16);
  asm volatile("" ::: "memory");          // pin loads before staging

  // ---- prologue staging: K0, A0, K1, A1 (3+3 loads)
  stageK(0, Ks0); stageA(0, Ab0);
  stageK(1, Ks1); stageA(1, Ab1);
  asm volatile("s_waitcnt vmcnt(3)" ::: "memory");   // Q,mask,K0,A0 done
  __builtin_amdgcn_sched_barrier(0);

  float ls = 0.0f;

  // ---- QK loop: 8 per-wave iterations, no barriers
  #pragma unroll
  for (int t = 0; t < 8; ++t) {
    if (t == 7)     asm volatile("s_waitcnt vmcnt(2)" ::: "memory");
    else if (t > 0) asm volatile("s_waitcnt vmcnt(3)" ::: "memory");
    __builtin_amdgcn_sched_barrier(0);

    const char* kb = (t & 1) ? Ks1 : Ks0;
    const char* ab = (t & 1) ? Ab1 : Ab0;
    bf16x8 kf0 = *(const bf16x8*)(kb + fr * 128 + ((kg * 16) ^ frsw));
    bf16x8 kf1 = *(const bf16x8*)(kb + fr * 128 + ((64 + kg * 16) ^ frsw));
    f32x4 a4  = *(const f32x4*)(ab + fr * 64 + kg * 16);

    asm volatile("s_waitcnt lgkmcnt(0)" ::: "memory");  // buffers free
    __builtin_amdgcn_sched_barrier(0);

    if (t < 6)      { stageK(t + 2, (t & 1) ? Ks1 : Ks0);
                      stageA(t + 2, (t & 1) ? Ab1 : Ab0); }
    else if (t == 6)  stageV(0, Ks0);   // K0 just consumed
    else              stageV(1, Ks1);   // K1 just consumed

    __builtin_amdgcn_s_setprio(1);
    f32x4 s = (f32x4)0.0f;
    s = __builtin_amdgcn_mfma_f32_16x16x32_bf16(kf0, qf0, s, 0, 0, 0);
    s = __builtin_amdgcn_mfma_f32_16x16x32_bf16(kf1, qf1, s, 0, 0, 0);
    __builtin_amdgcn_s_setprio(0);

    f32x4 p;
    #pragma unroll
    for (int r = 0; r < 4; ++r)
      p[r] = __expf(s[r] + a4[r] + mreg[t][r] * (-1e9f));
    ls += (p[0] + p[1]) + (p[2] + p[3]);
    u16x4 pk;
    #pragma unroll
    for (int r = 0; r < 4; ++r) pk[r] = f2bf(p[r]);
    *(u16x4*)(Pb + fr * 2048 + ((kw * 2 + t * 32 + kg * 8) ^ frsw)) = pk;
  }

  // ---- strip sums -> own A0 slot
  ls += __shfl_xor(ls, 16);
  ls += __shfl_xor(ls, 32);
  if (lane < 16) *(float*)(Ab0 + lane * 4) = ls;

  // ---- mid barrier: P + ssum visible; V0,V1 still in flight
  asm volatile("s_waitcnt lgkmcnt(0)" ::: "memory");
  __builtin_amdgcn_s_barrier();
  __builtin_amdgcn_sched_barrier(0);

  // ---- PV loop: 8 per-wave iterations of 64k, no barriers
  f32x4 cacc = (f32x4)0.0f;
  #pragma unroll
  for (int t = 0; t < 8; ++t) {
    if (t == 7) asm volatile("s_waitcnt vmcnt(0)" ::: "memory");
    else        asm volatile("s_waitcnt vmcnt(2)" ::: "memory");
    __builtin_amdgcn_sched_barrier(0);

    const char* vb = (t & 1) ? Ks1 : Ks0;
    bf16x8 vf0 = *(const bf16x8*)(vb + fr * 128 + ((kg * 16) ^ frsw));
    bf16x8 vf1 = *(const bf16x8*)(vb + fr * 128 + ((64 + kg * 16) ^ frsw));
    bf16x8 pf0 = *(const bf16x8*)(Pb + fr * 2048 + ((kh * 1024 + t * 128 + kg * 16) ^ frsw));
    bf16x8 pf1 = *(const bf16x8*)(Pb + fr * 2048 + ((kh * 1024 + t * 128 + 64 + kg * 16) ^ frsw));

    asm volatile("s_waitcnt lgkmcnt(0)" ::: "memory");
    __builtin_amdgcn_sched_barrier(0);

    if (t < 6) stageV(t + 2, (t & 1) ? Ks1 : Ks0);

    __builtin_amdgcn_s_setprio(1);
    cacc = __builtin_amdgcn_mfma_f32_16x16x32_bf16(vf0, pf0, cacc, 0, 0, 0);
    cacc = __builtin_amdgcn_mfma_f32_16x16x32_bf16(vf1, pf1, cacc, 0, 0, 0);
    __builtin_amdgcn_s_setprio(0);
  }

  // ---- epilogue: waves 4-7 publish k-half partials; 0-3 reduce + ctx
  if (w >= 4) *(f32x4*)(Ab1 + lane * 16) = cacc;
  asm volatile("s_waitcnt lgkmcnt(0)" ::: "memory");
  __builtin_amdgcn_s_barrier();
  __builtin_amdgcn_sched_barrier(0);

  if (w < 4) {
    f32x4 red = *(const f32x4*)(Rg + (w + 4) * 6144 + 5120 + lane * 16);
    #pragma unroll
    for (int r = 0; r < 4; ++r) cacc[r] += red[r];
    float gs = 0.0f;
    #pragma unroll
    for (int w2 = 0; w2 < 8; ++w2)
      gs += *(const float*)(Rg + w2 * 6144 + 4096 + fr * 4);
    const float giC = 1.0f / gs;
    u16x4 cv;
    #pragma unroll
    for (int r = 0; r < 4; ++r) cv[r] = f2bf(cacc[r] * giC);
    *(u16x4*)&ctx[((size_t)b * S_ + q0 + fr) * D_ + h * DEPTH_ + fd * 16 + kg * 4] = cv;
  }

  // ---- attn store: 2 rows/wave from P-LDS, nontemporal full-line stores
  #pragma unroll
  for (int j = 0; j < 2; ++j) {
    const int row = w * 2 + j;
    float gs = 0.0f;
    #pragma unroll
    for (int w2 = 0; w2 < 8; ++w2)
      gs += *(const float*)(Rg + w2 * 6144 + 4096 + row * 4);
    const float g = 1.0f / gs;
    const char* pr = Pb + row * 2048;
    const int rs = (row & 7) << 4;
    float* ao = attn_out + ((size_t)bh * S_ + q0 + row) * S_;
    #pragma unroll
    for (int half = 0; half < 2; ++half) {
      u16x8 pv = *(const u16x8*)(pr + ((half * 1024 + lane * 16) ^ rs));
      f32x4 o0, o1;
      #pragma unroll
      for (int e = 0; e < 4; ++e) { o0[e] = bf2f(pv[e]) * g; o1[e] = bf2f(pv[4 + e]) * g; }
      __builtin_nontemporal_store(o0, (f32x4*)(ao + half * 512 + lane * 8));
      __builtin_nontemporal_store(o1, (f32x4*)(ao + half * 512 + lane * 8 + 4));
    }
  }
}

// ---------------- launcher ----------------
extern "C" void kernel_launch(void* const* d_in, const int* in_sizes, int n_in,
                              void* d_out, int out_size, void* d_ws, size_t ws_size,
                              hipStream_t stream)
{
  const float* v_in   = (const float*)d_in[0];
  const float* k_in   = (const float*)d_in[1];
  const float* q_in   = (const float*)d_in[2];
  const float* mask   = (const float*)d_in[3];
  const float* adjoin = (const float*)d_in[4];
  const float* wq_w   = (const float*)d_in[5];
  const float* wq_b   = (const float*)d_in[6];
  const float* wk_w   = (const float*)d_in[7];
  const float* wk_b   = (const float*)d_in[8];
  const float* wv_w   = (const float*)d_in[9];
  const float* wv_b   = (const float*)d_in[10];
  const float* wd_w   = (const float*)d_in[11];
  const float* wd_b   = (const float*)d_in[12];

  unsigned short* xq  = (unsigned short*)d_ws;      // unused (kept for layout)
  unsigned short* xk  = xq  + (size_t)M_ * D_;      // unused
  unsigned short* xv  = xk  + (size_t)M_ * D_;
  unsigned short* wqb = xv  + (size_t)M_ * D_;
  unsigned short* wkb = wqb + (size_t)D_ * D_;
  unsigned short* wvb = wkb + (size_t)D_ * D_;
  unsigned short* wdb = wvb + (size_t)D_ * D_;
  unsigned short* qp  = wdb + (size_t)D_ * D_;
  unsigned short* kp  = qp  + (size_t)M_ * D_;
  unsigned short* vt  = kp  + (size_t)M_ * D_;
  unsigned short* ctx = vt  + (size_t)M_ * D_;

  float* out  = (float*)d_out;                       // [B,S,D]
  float* attn = out + (size_t)B_ * S_ * D_;          // [B,H,S,S]

  CvtAll ca;
  ca.s[0] = v_in; ca.s[1] = wq_w; ca.s[2] = wk_w; ca.s[3] = wv_w; ca.s[4] = wd_w;
  ca.d[0] = xv;   ca.d[1] = wqb;  ca.d[2] = wkb;  ca.d[3] = wvb;  ca.d[4] = wdb;
  cvt_all_kernel<<<4096, 256, 0, stream>>>(ca);

  GemmSet sq{nullptr, q_in, wqb, qp, wq_b};   // convert-on-stage
  GemmSet sk{nullptr, k_in, wkb, kp, wk_b};   // convert-on-stage
  GemmSet sv{wvb, nullptr, xv,  vt, wv_b};    // V^T: bf16 A
  qkv_gemm<<<dim3(256, 3), 256, 0, stream>>>(sq, sk, sv);

  attn_kernel<<<B_ * H_ * (S_ / 16), 512, 0, stream>>>(qp, kp, vt, mask, adjoin, attn, ctx);

  dense_gemm<<<dim3(64, 8), 256, 0, stream>>>(ctx, wdb, out, wd_b);
}